// Round 3
// baseline (832.670 us; speedup 1.0000x reference)
//
#include <hip/hip_runtime.h>
#include <math.h>

#define D_IN  512
#define D_HID 16
#define D_OUT 64
#define NBLK  256   // partition blocks
#define BKT   256   // nodes per bucket

// ---------------------------------------------------------------------------
// P1: per-block histogram of dst buckets -> counts[bucket][block]
__global__ __launch_bounds__(256) void k_hist(const int* __restrict__ dst,
                                              int* __restrict__ counts, int E, int NB) {
    __shared__ int h[512];
    int t = threadIdx.x;
    for (int i = t; i < NB; i += 256) h[i] = 0;
    __syncthreads();
    int per = (E + NBLK - 1) / NBLK;
    int e0 = blockIdx.x * per, e1 = min(E, e0 + per);
    for (int e = e0 + t; e < e1; e += 256) atomicAdd(&h[dst[e] >> 8], 1);
    __syncthreads();
    for (int i = t; i < NB; i += 256) counts[i * NBLK + blockIdx.x] = h[i];
}

// bucket totals
__global__ __launch_bounds__(256) void k_btot(const int* __restrict__ counts,
                                              int* __restrict__ btot, int NB) {
    __shared__ int s[256];
    int t = threadIdx.x;
    s[t] = counts[blockIdx.x * NBLK + t];
    __syncthreads();
    for (int off = 128; off; off >>= 1) { if (t < off) s[t] += s[t + off]; __syncthreads(); }
    if (t == 0) btot[blockIdx.x] = s[0];
}

// exclusive scan of bucket totals -> boff[NB+1]
__global__ __launch_bounds__(512) void k_boff(const int* __restrict__ btot,
                                              int* __restrict__ boff, int NB) {
    __shared__ int s[512];
    int t = threadIdx.x;
    int v = (t < NB) ? btot[t] : 0;
    s[t] = v; __syncthreads();
    for (int off = 1; off < 512; off <<= 1) {
        int u = (t >= off) ? s[t - off] : 0;
        __syncthreads(); s[t] += u; __syncthreads();
    }
    if (t < NB) boff[t] = s[t] - v;
    if (t == NB - 1) boff[NB] = s[t];
}

// counts[b][blk] -> global cursor base (boff[b] + exclusive scan over blocks)
__global__ __launch_bounds__(256) void k_cursor(int* __restrict__ counts,
                                                const int* __restrict__ boff, int NB) {
    __shared__ int s[256];
    int b = blockIdx.x, t = threadIdx.x;
    int v = counts[b * NBLK + t];
    s[t] = v; __syncthreads();
    for (int off = 1; off < 256; off <<= 1) {
        int u = (t >= off) ? s[t - off] : 0;
        __syncthreads(); s[t] += u; __syncthreads();
    }
    counts[b * NBLK + t] = boff[b] + s[t] - v;
}

// P3: scatter packed edges (src<<8 | dst&255) into bucket-contiguous regions
__global__ __launch_bounds__(256) void k_part(const int* __restrict__ src,
                                              const int* __restrict__ dst,
                                              const int* __restrict__ counts,
                                              unsigned int* __restrict__ packed,
                                              int E, int NB) {
    __shared__ int cur[512];
    int t = threadIdx.x;
    for (int i = t; i < NB; i += 256) cur[i] = counts[i * NBLK + blockIdx.x];
    __syncthreads();
    int per = (E + NBLK - 1) / NBLK;
    int e0 = blockIdx.x * per, e1 = min(E, e0 + per);
    for (int e = e0 + t; e < e1; e += 256) {
        int d = dst[e];
        int slot = atomicAdd(&cur[d >> 8], 1);
        packed[slot] = ((unsigned int)src[e] << 8) | (unsigned int)(d & 255);
    }
}

// per-node degree from packed buckets -> dis = rsqrt(deg+1)
__global__ __launch_bounds__(256) void k_dis(const unsigned int* __restrict__ packed,
                                             const int* __restrict__ boff,
                                             float* __restrict__ dis, int n) {
    __shared__ int c[BKT];
    int b = blockIdx.x, t = threadIdx.x;
    c[t] = 0; __syncthreads();
    int e0 = boff[b], e1 = boff[b + 1];
    for (int e = e0 + t; e < e1; e += 256) atomicAdd(&c[packed[e] & 255], 1);
    __syncthreads();
    int node = b * BKT + t;
    if (node < n) dis[node] = rsqrtf((float)(c[t] + 1));
}

// m1[r][j] = dis[r] * sum_k x[r][k] * W1[k][j]; 4 threads per row.
__global__ __launch_bounds__(256) void k_gemm1(const float* __restrict__ x,
                                               const float* __restrict__ W1,
                                               const float* __restrict__ dis,
                                               float* __restrict__ m1, int n) {
    __shared__ float w[D_IN * D_HID];  // 32 KiB
    for (int i = threadIdx.x; i < (D_IN * D_HID) / 4; i += 256)
        ((float4*)w)[i] = ((const float4*)W1)[i];
    __syncthreads();

    int gid  = blockIdx.x * blockDim.x + threadIdx.x;
    int row  = gid >> 2;
    int part = gid & 3;
    if (row >= n) return;

    const float4* xr = (const float4*)(x + (size_t)row * D_IN + part * 128);
    float acc[D_HID];
#pragma unroll
    for (int j = 0; j < D_HID; j++) acc[j] = 0.0f;

#pragma unroll 4
    for (int m = 0; m < 32; m++) {
        float4 xv = xr[m];
        int kb = part * 128 + m * 4;
        const float* w0 = &w[(kb + 0) * D_HID];
        const float* w1 = &w[(kb + 1) * D_HID];
        const float* w2 = &w[(kb + 2) * D_HID];
        const float* w3 = &w[(kb + 3) * D_HID];
#pragma unroll
        for (int j = 0; j < D_HID; j++)
            acc[j] += xv.x * w0[j] + xv.y * w1[j] + xv.z * w2[j] + xv.w * w3[j];
    }
#pragma unroll
    for (int j = 0; j < D_HID; j++) {
        acc[j] += __shfl_xor(acc[j], 1);
        acc[j] += __shfl_xor(acc[j], 2);
    }
    float s = dis[row];
    float4 o;
    o.x = s * acc[part * 4 + 0];
    o.y = s * acc[part * 4 + 1];
    o.z = s * acc[part * 4 + 2];
    o.w = s * acc[part * 4 + 3];
    ((float4*)(m1 + (size_t)row * D_HID))[part] = o;
}

// aggregation: block (bucket b, slice s) accumulates msg rows into LDS tile.
// acc layout is bank-swizzled: column-group q of node dl lives at dl*16 + (q^(dl&3))*4.
__global__ __launch_bounds__(256) void k_agg(const unsigned int* __restrict__ packed,
                                             const int* __restrict__ boff,
                                             const float* __restrict__ msg,
                                             float* __restrict__ partial, int S) {
    __shared__ float acc[BKT * D_HID];  // 16 KiB
    int t = threadIdx.x;
    int b = blockIdx.x / S, s = blockIdx.x % S;
    for (int i = t; i < BKT * D_HID; i += 256) acc[i] = 0.0f;
    __syncthreads();

    int e0 = boff[b];
    int len = boff[b + 1] - e0;
    int a0 = (int)((long long)len * s / S);
    int a1 = (int)((long long)len * (s + 1) / S);

    int q = t & 3, g = t >> 2;  // 64 edge-groups of 4 lanes
    for (int i = a0 + g; i < a1; i += 64) {
        unsigned int v = packed[e0 + i];
        int dl = v & 255;
        const float4 m4 = ((const float4*)(msg + (size_t)(v >> 8) * D_HID))[q];
        float* a = &acc[dl * D_HID + ((q ^ (dl & 3)) << 2)];
        atomicAdd(a + 0, m4.x);
        atomicAdd(a + 1, m4.y);
        atomicAdd(a + 2, m4.z);
        atomicAdd(a + 3, m4.w);
    }
    __syncthreads();
    float4* p4 = (float4*)(partial + (size_t)blockIdx.x * (BKT * D_HID));
    const float4* a4 = (const float4*)acc;
    for (int i = t; i < (BKT * D_HID) / 4; i += 256) p4[i] = a4[i];
}

// merge layer 1: outb = dis*relu(dis*(sum partials + m1_self) + b1)
__global__ __launch_bounds__(256) void k_merge1(const float* __restrict__ partial,
                                                const float* __restrict__ m1,
                                                const float* __restrict__ dis,
                                                const float* __restrict__ b1,
                                                float* __restrict__ outb, int n, int S) {
    int tid = blockIdx.x * blockDim.x + threadIdx.x;
    int node = tid >> 2, q = tid & 3;
    if (node >= n) return;
    int b = node >> 8, l = node & 255;
    float4 a = ((const float4*)(m1 + (size_t)node * D_HID))[q];
    int qs = q ^ (l & 3);
    for (int s = 0; s < S; s++) {
        const float4 p = ((const float4*)(partial + ((size_t)(b * S + s)) * (BKT * D_HID)
                                          + (size_t)l * D_HID))[qs];
        a.x += p.x; a.y += p.y; a.z += p.z; a.w += p.w;
    }
    float di = dis[node];
    const float4 bb = ((const float4*)b1)[q];
    float4 o;
    o.x = di * fmaxf(di * a.x + bb.x, 0.0f);
    o.y = di * fmaxf(di * a.y + bb.y, 0.0f);
    o.z = di * fmaxf(di * a.z + bb.z, 0.0f);
    o.w = di * fmaxf(di * a.w + bb.w, 0.0f);
    ((float4*)(outb + (size_t)node * D_HID))[q] = o;
}

// merge layer 2: g = dis*(sum partials + msg_self)
__global__ __launch_bounds__(256) void k_merge2(const float* __restrict__ partial,
                                                const float* __restrict__ msg,
                                                const float* __restrict__ dis,
                                                float* __restrict__ g, int n, int S) {
    int tid = blockIdx.x * blockDim.x + threadIdx.x;
    int node = tid >> 2, q = tid & 3;
    if (node >= n) return;
    int b = node >> 8, l = node & 255;
    float4 a = ((const float4*)(msg + (size_t)node * D_HID))[q];
    int qs = q ^ (l & 3);
    for (int s = 0; s < S; s++) {
        const float4 p = ((const float4*)(partial + ((size_t)(b * S + s)) * (BKT * D_HID)
                                          + (size_t)l * D_HID))[qs];
        a.x += p.x; a.y += p.y; a.z += p.z; a.w += p.w;
    }
    float di = dis[node];
    float4 o;
    o.x = di * a.x; o.y = di * a.y; o.z = di * a.z; o.w = di * a.w;
    ((float4*)(g + (size_t)node * D_HID))[q] = o;
}

// out_row = g @ W2 + b2, then log_softmax over 64 lanes (one wave per node)
__global__ __launch_bounds__(256) void k_final(const float* __restrict__ g,
                                               const float* __restrict__ W2,
                                               const float* __restrict__ b2,
                                               float* __restrict__ out, int n) {
    int lane = threadIdx.x & 63;
    int node = blockIdx.x * 4 + (threadIdx.x >> 6);
    if (node >= n) return;

    float gv[D_HID];
    const float4* g4 = (const float4*)(g + (size_t)node * D_HID);
#pragma unroll
    for (int q = 0; q < 4; q++) {
        float4 v4 = g4[q];
        gv[q * 4 + 0] = v4.x; gv[q * 4 + 1] = v4.y;
        gv[q * 4 + 2] = v4.z; gv[q * 4 + 3] = v4.w;
    }
    float v = b2[lane];
#pragma unroll
    for (int j = 0; j < D_HID; j++) v += gv[j] * W2[j * D_OUT + lane];

    float mx = v;
#pragma unroll
    for (int off = 32; off; off >>= 1) mx = fmaxf(mx, __shfl_xor(mx, off));
    float ev = expf(v - mx);
    float sum = ev;
#pragma unroll
    for (int off = 32; off; off >>= 1) sum += __shfl_xor(sum, off);
    out[(size_t)node * D_OUT + lane] = (v - mx) - logf(sum);
}

// ---------------------------------------------------------------------------
extern "C" void kernel_launch(void* const* d_in, const int* in_sizes, int n_in,
                              void* d_out, int out_size, void* d_ws, size_t ws_size,
                              hipStream_t stream) {
    const float* x  = (const float*)d_in[0];
    const int*   ei = (const int*)d_in[1];
    const float* W1 = (const float*)d_in[2];
    const float* b1 = (const float*)d_in[3];
    const float* W2 = (const float*)d_in[4];
    const float* b2 = (const float*)d_in[5];
    float* out = (float*)d_out;

    int n = in_sizes[0] / D_IN;   // 100000
    int E = in_sizes[1] / 2;      // 3200000
    const int* src = ei;
    const int* dst = ei + E;
    int NB = (n + BKT - 1) / BKT; // 391

    size_t off = 0;
    int* counts = (int*)d_ws;                 off += (size_t)NB * NBLK;
    int* btot   = (int*)d_ws + off;           off += NB;
    int* boff   = (int*)d_ws + off;           off += NB + 1;
    unsigned int* packed = (unsigned int*)d_ws + off; off += E;
    float* dis  = (float*)d_ws + off;         off += n;
    float* bufA = (float*)d_ws + off;         off += (size_t)n * D_HID;
    float* bufB = (float*)d_ws + off;         off += (size_t)n * D_HID;
    float* partial = (float*)d_ws + off;

    // pick slice count deterministically from available workspace
    size_t avail = ws_size / 4 - off;
    int S = 4;
    while (S > 1 && avail < (size_t)S * NB * (BKT * D_HID)) S >>= 1;

    const int B = 256;
    k_hist  <<<NBLK, B, 0, stream>>>(dst, counts, E, NB);
    k_btot  <<<NB, B, 0, stream>>>(counts, btot, NB);
    k_boff  <<<1, 512, 0, stream>>>(btot, boff, NB);
    k_cursor<<<NB, B, 0, stream>>>(counts, boff, NB);
    k_part  <<<NBLK, B, 0, stream>>>(src, dst, counts, packed, E, NB);
    k_dis   <<<NB, B, 0, stream>>>(packed, boff, dis, n);
    k_gemm1 <<<(n * 4 + B - 1) / B, B, 0, stream>>>(x, W1, dis, bufA, n);
    k_agg   <<<NB * S, B, 0, stream>>>(packed, boff, bufA, partial, S);
    k_merge1<<<(n * 4 + B - 1) / B, B, 0, stream>>>(partial, bufA, dis, b1, bufB, n, S);
    k_agg   <<<NB * S, B, 0, stream>>>(packed, boff, bufB, partial, S);
    k_merge2<<<(n * 4 + B - 1) / B, B, 0, stream>>>(partial, bufB, dis, bufA, n, S);
    k_final <<<(n + 3) / 4, B, 0, stream>>>(bufA, W2, b2, out, n);
}